// Round 1
// baseline (303.975 us; speedup 1.0000x reference)
//
#include <hip/hip_runtime.h>
#include <cfloat>
#include <math.h>

#define NB   16
#define NGT  60
#define NA   8400
#define NCLS 80
#define KNN  10
#define NCAND (NGT*KNN)   // 600
#define EPSF 1e-7f
#define PIF  3.14159265358979f

__device__ __forceinline__ float sigm(float x){ return 1.0f/(1.0f+expf(-x)); }
__device__ __forceinline__ float softplusf_(float x){ return fmaxf(x,0.f)+log1pf(expf(-fabsf(x))); }

// anchor -> pointer to its 84-channel row in the right level tensor
__device__ __forceinline__ const float* anchor_base(const float* p0,const float* p1,const float* p2,int img,int a){
  if (a < 6400) return p0 + (size_t)(img*6400 + a)*84;
  if (a < 8000) return p1 + (size_t)(img*1600 + (a-6400))*84;
  return p2 + (size_t)(img*400 + (a-8000))*84;
}

__global__ void zero_acc(float* acc){ if (threadIdx.x < 16) acc[threadIdx.x] = 0.f; }

// decode all anchors: boxes[img*NA+a] = (px,py,pw,ph)
__global__ void decode_kernel(const float* __restrict__ p0, const float* __restrict__ p1,
                              const float* __restrict__ p2, float4* __restrict__ boxes){
  int t = blockIdx.x*blockDim.x + threadIdx.x;
  if (t >= NB*NA) return;
  int img = t / NA, a = t - img*NA;
  const float* p; int S; float stride; int local;
  if (a < 6400)      { p=p0; S=80; stride= 8.f; local=a; }
  else if (a < 8000) { p=p1; S=40; stride=16.f; local=a-6400; }
  else               { p=p2; S=20; stride=32.f; local=a-8000; }
  int i = local / S, j = local - i*S;
  const float* q = p + (size_t)(img*S*S + local)*84;
  float tx=q[0], ty=q[1], tw=q[2], th=q[3];
  float px = (sigm(tx)*2.f - 0.5f + (float)j)*stride;
  float py = (sigm(ty)*2.f - 0.5f + (float)i)*stride;
  float pw = softplusf_(tw)*stride;
  float ph = softplusf_(th)*stride;
  boxes[t] = make_float4(px,py,pw,ph);
}

// one wave (64 lanes) per (img,gt): 10 nearest anchors by center distance
__global__ __launch_bounds__(64) void topk_kernel(const float4* __restrict__ boxes,
                                                  const float* __restrict__ gt,
                                                  int* __restrict__ cand){
  int pair = blockIdx.x;              // 0 .. NB*NGT-1
  int img = pair / NGT, g = pair - img*NGT;
  int lane = threadIdx.x;
  const float* gb = gt + (size_t)(img*NGT + g)*4;
  float tcx = (gb[0]+gb[2])*0.5f, tcy = (gb[1]+gb[3])*0.5f;

  float d[KNN]; int id[KNN];
  #pragma unroll
  for (int k=0;k<KNN;k++){ d[k]=FLT_MAX; id[k]=-1; }

  const float4* bb = boxes + (size_t)img*NA;
  for (int a=lane; a<NA; a+=64){
    float4 b = bb[a];
    float dx=b.x-tcx, dy=b.y-tcy;
    float dist = dx*dx + dy*dy;
    if (dist < d[KNN-1]){
      int k = KNN-1;
      while (k>0 && d[k-1] > dist){ d[k]=d[k-1]; id[k]=id[k-1]; k--; }
      d[k]=dist; id[k]=a;
    }
  }
  // merge: 10 rounds of wave argmin over each lane's current head
  int pos = 0;
  for (int r=0;r<KNN;r++){
    float v   = (pos<KNN)? d[pos] : FLT_MAX;
    int  anc  = (pos<KNN)? id[pos] : -1;
    int  src  = lane;
    #pragma unroll
    for (int off=32; off>0; off>>=1){
      float v2 = __shfl_xor(v, off);
      int  a2 = __shfl_xor(anc, off);
      int  s2 = __shfl_xor(src, off);
      if (v2 < v || (v2==v && s2<src)){ v=v2; anc=a2; src=s2; }
    }
    if (lane == src) pos++;
    if (lane == 0) cand[(size_t)(img*NGT+g)*KNN + r] = anc;
  }
}

// one block per image: cost argmin -> matched, then ciou sum + focal corrections
__global__ __launch_bounds__(256) void match_kernel(const float4* __restrict__ boxes,
                                                    const int* __restrict__ cand,
                                                    const float* __restrict__ gt,
                                                    const int* __restrict__ labels,
                                                    const float* __restrict__ p0,
                                                    const float* __restrict__ p1,
                                                    const float* __restrict__ p2,
                                                    float* acc){
  int img = blockIdx.x;
  int tid = threadIdx.x;
  __shared__ float4 cb[NCAND];   // candidate boxes, xyxy
  __shared__ int    cidx[NCAND];
  __shared__ float4 gbox[NGT];
  __shared__ float  garea[NGT];
  __shared__ int    glab[NGT];
  __shared__ int    matched[NGT];
  __shared__ float  rcost[256];
  __shared__ int    rix[256];

  for (int c=tid; c<NCAND; c+=256){
    int a = cand[(size_t)img*NCAND + c];
    cidx[c] = a;
    float4 b = boxes[(size_t)img*NA + a];
    cb[c] = make_float4(b.x - b.z*0.5f, b.y - b.w*0.5f, b.x + b.z*0.5f, b.y + b.w*0.5f);
  }
  for (int j=tid; j<NGT; j+=256){
    const float* gb = gt + (size_t)(img*NGT + j)*4;
    float4 g = make_float4(gb[0],gb[1],gb[2],gb[3]);
    gbox[j]  = g;
    garea[j] = fmaxf(g.z-g.x,0.f)*fmaxf(g.w-g.y,0.f);
    glab[j]  = labels[img*NGT + j];
  }
  __syncthreads();

  for (int j=0; j<NGT; j++){
    float4 g = gbox[j]; float a2 = garea[j]; int lab = glab[j];
    float best = FLT_MAX; int bix = 1<<30;
    for (int c=tid; c<NCAND; c+=256){
      float4 b = cb[c];
      float a1 = fmaxf(b.z-b.x,0.f)*fmaxf(b.w-b.y,0.f);
      float ix1=fmaxf(b.x,g.x), iy1=fmaxf(b.y,g.y);
      float ix2=fminf(b.z,g.z), iy2=fminf(b.w,g.w);
      float inter = fmaxf(ix2-ix1,0.f)*fmaxf(iy2-iy1,0.f);
      float uni = a1 + a2 - inter + EPSF;
      float iou = fminf(fmaxf(inter/uni,0.f),1.f);
      float lg = anchor_base(p0,p1,p2,img,cidx[c])[4+lab];
      float cost = 0.5f*(1.f - sigm(lg)) + 6.f*(1.f - iou);
      if (cost < best){ best=cost; bix=c; }   // c increasing -> first-occurrence on ties
    }
    rcost[tid]=best; rix[tid]=bix;
    __syncthreads();
    for (int s=128; s>0; s>>=1){
      if (tid < s){
        if (rcost[tid+s] < rcost[tid] || (rcost[tid+s]==rcost[tid] && rix[tid+s]<rix[tid])){
          rcost[tid]=rcost[tid+s]; rix[tid]=rix[tid+s];
        }
      }
      __syncthreads();
    }
    if (tid==0) matched[j] = cidx[rix[0]];
    __syncthreads();
  }

  // ciou loss + focal corrections (dedup'd (anchor,label) pairs)
  float local_box = 0.f, local_corr = 0.f;
  if (tid < NGT){
    int j = tid;
    int m = matched[j];
    float4 pb = boxes[(size_t)img*NA + m];
    float px1=pb.x-pb.z*0.5f, py1=pb.y-pb.w*0.5f, px2=pb.x+pb.z*0.5f, py2=pb.y+pb.w*0.5f;
    float4 g = gbox[j];
    float pw=fmaxf(px2-px1,EPSF), ph=fmaxf(py2-py1,EPSF);
    float tw=fmaxf(g.z-g.x,EPSF), th=fmaxf(g.w-g.y,EPSF);
    float inter = fmaxf(fminf(px2,g.z)-fmaxf(px1,g.x),0.f)*fmaxf(fminf(py2,g.w)-fmaxf(py1,g.y),0.f);
    float uni = pw*ph + tw*th - inter + EPSF;
    float iou = inter/uni;
    float dcx = (px1+px2)*0.5f - (g.x+g.z)*0.5f;
    float dcy = (py1+py2)*0.5f - (g.y+g.w)*0.5f;
    float cd = dcx*dcx + dcy*dcy;
    float cw = fmaxf(px2,g.z) - fminf(px1,g.x);
    float ch = fmaxf(py2,g.w) - fminf(py1,g.y);
    float c2 = cw*cw + ch*ch + EPSF;
    float dv = atanf(tw/th) - atanf(pw/ph);
    float v  = (4.f/(PIF*PIF))*dv*dv;
    float alpha = v/(v - iou + 1.f + EPSF);
    float ciou = iou - cd/c2 - alpha*v;
    local_box = 1.f - ciou;

    int lab = glab[j];
    bool dup = false;
    for (int j2=0; j2<j; j2++)
      if (matched[j2]==m && glab[j2]==lab){ dup=true; break; }
    if (!dup){
      float x = anchor_base(p0,p1,p2,img,m)[4+lab];
      float s  = sigm(x);
      float sp_pos = fmaxf(-x,0.f)+log1pf(expf(-fabsf(x)));  // softplus(-x) == ce for tgt=1
      float sp_neg = fmaxf( x,0.f)+log1pf(expf(-fabsf(x)));  // softplus(x)  == ce for tgt=0
      float t1 = 0.25f*sp_pos*(1.f-s)*(1.f-s);
      float t0 = 0.75f*sp_neg*s*s;
      local_corr = t1 - t0;
    }
  }
  rcost[tid] = local_box; __syncthreads();
  for (int s=128; s>0; s>>=1){ if (tid<s) rcost[tid]+=rcost[tid+s]; __syncthreads(); }
  if (tid==0) atomicAdd(acc+0, rcost[0]);
  __syncthreads();
  rcost[tid] = local_corr; __syncthreads();
  for (int s=128; s>0; s>>=1){ if (tid<s) rcost[tid]+=rcost[tid+s]; __syncthreads(); }
  if (tid==0) atomicAdd(acc+2, rcost[0]);
}

// background focal term over one level tensor (skips box channels)
__global__ __launch_bounds__(256) void focal_bg_kernel(const float* __restrict__ p, unsigned int n, float* acc){
  __shared__ float sbuf[256];
  float sum = 0.f;
  unsigned int stride = gridDim.x*blockDim.x;
  for (unsigned int t = blockIdx.x*blockDim.x + threadIdx.x; t < n; t += stride){
    unsigned int ch = t % 84u;
    float x = p[t];
    if (ch >= 4u){
      float sp = fmaxf(x,0.f)+log1pf(expf(-fabsf(x)));
      float s  = 1.0f/(1.0f+expf(-x));
      sum += sp*s*s;
    }
  }
  sum *= 0.75f;
  sbuf[threadIdx.x]=sum; __syncthreads();
  for (int s=128; s>0; s>>=1){ if ((int)threadIdx.x<s) sbuf[threadIdx.x]+=sbuf[threadIdx.x+s]; __syncthreads(); }
  if (threadIdx.x==0) atomicAdd(acc+1, sbuf[0]);
}

__global__ void finalize_kernel(const float* acc, float* out){
  out[0] = (7.5f*acc[0] + 0.5f*(acc[1]+acc[2])) / (60.f*16.f);
}

extern "C" void kernel_launch(void* const* d_in, const int* in_sizes, int n_in,
                              void* d_out, int out_size, void* d_ws, size_t ws_size,
                              hipStream_t stream){
  const float* p0 = (const float*)d_in[0];
  const float* p1 = (const float*)d_in[1];
  const float* p2 = (const float*)d_in[2];
  const float* gt = (const float*)d_in[3];
  const int* labels = (const int*)d_in[4];
  float* out = (float*)d_out;

  // workspace layout
  float*  acc   = (float*)d_ws;                       // 16 floats
  float4* boxes = (float4*)((char*)d_ws + 64);        // NB*NA float4 = 2.15 MB
  int*    cand  = (int*)((char*)d_ws + 64 + (size_t)NB*NA*sizeof(float4)); // NB*600 ints

  zero_acc<<<1, 64, 0, stream>>>(acc);
  decode_kernel<<<(NB*NA + 255)/256, 256, 0, stream>>>(p0, p1, p2, boxes);
  topk_kernel<<<NB*NGT, 64, 0, stream>>>(boxes, gt, cand);
  match_kernel<<<NB, 256, 0, stream>>>(boxes, cand, gt, labels, p0, p1, p2, acc);
  focal_bg_kernel<<<1024, 256, 0, stream>>>(p0, (unsigned int)(NB*6400*84), acc);
  focal_bg_kernel<<<512, 256, 0, stream>>>(p1, (unsigned int)(NB*1600*84), acc);
  focal_bg_kernel<<<256, 256, 0, stream>>>(p2, (unsigned int)(NB*400*84), acc);
  finalize_kernel<<<1, 1, 0, stream>>>(acc, out);
}

// Round 2
// 207.275 us; speedup vs baseline: 1.4665x; 1.4665x over previous
//
#include <hip/hip_runtime.h>
#include <cfloat>
#include <math.h>

#define NB   16
#define NGT  60
#define NA   8400
#define NCLS 80
#define KNN  10
#define NCAND (NGT*KNN)   // 600
#define EPSF 1e-7f
#define PIF  3.14159265358979f

__device__ __forceinline__ float sigm(float x){ return 1.0f/(1.0f+expf(-x)); }
__device__ __forceinline__ float softplusf_(float x){ return fmaxf(x,0.f)+log1pf(expf(-fabsf(x))); }

// anchor -> pointer to its 84-channel row in the right level tensor
__device__ __forceinline__ const float* anchor_base(const float* p0,const float* p1,const float* p2,int img,int a){
  if (a < 6400) return p0 + (size_t)(img*6400 + a)*84;
  if (a < 8000) return p1 + (size_t)(img*1600 + (a-6400))*84;
  return p2 + (size_t)(img*400 + (a-8000))*84;
}

// decode all anchors: boxes[img*NA+a] = (px,py,pw,ph); block 0 also zeroes acc
__global__ __launch_bounds__(256) void decode_kernel(const float* __restrict__ p0, const float* __restrict__ p1,
                                                     const float* __restrict__ p2, float4* __restrict__ boxes,
                                                     float* acc){
  if (blockIdx.x == 0 && threadIdx.x < 16) acc[threadIdx.x] = 0.f;
  int t = blockIdx.x*blockDim.x + threadIdx.x;
  if (t >= NB*NA) return;
  int img = t / NA, a = t - img*NA;
  const float* p; int S; float stride; int local;
  if (a < 6400)      { p=p0; S=80; stride= 8.f; local=a; }
  else if (a < 8000) { p=p1; S=40; stride=16.f; local=a-6400; }
  else               { p=p2; S=20; stride=32.f; local=a-8000; }
  int i = local / S, j = local - i*S;
  const float* q = p + (size_t)(img*S*S + local)*84;
  float tx=q[0], ty=q[1], tw=q[2], th=q[3];
  float px = (sigm(tx)*2.f - 0.5f + (float)j)*stride;
  float py = (sigm(ty)*2.f - 0.5f + (float)i)*stride;
  float pw = softplusf_(tw)*stride;
  float ph = softplusf_(th)*stride;
  boxes[t] = make_float4(px,py,pw,ph);
}

// one wave per (img,gt): 10 nearest anchors by center distance. 4 waves/block.
__global__ __launch_bounds__(256) void topk_kernel(const float4* __restrict__ boxes,
                                                   const float* __restrict__ gt,
                                                   int* __restrict__ cand){
  int wid  = threadIdx.x >> 6;
  int lane = threadIdx.x & 63;
  int pair = blockIdx.x*4 + wid;          // 0 .. NB*NGT-1 (960, grid=240)
  int img = pair / NGT, g = pair - img*NGT;
  const float* gb = gt + (size_t)(img*NGT + g)*4;
  float tcx = (gb[0]+gb[2])*0.5f, tcy = (gb[1]+gb[3])*0.5f;

  float d[KNN]; int id[KNN];
  #pragma unroll
  for (int k=0;k<KNN;k++){ d[k]=FLT_MAX; id[k]=-1; }

  const float4* bb = boxes + (size_t)img*NA;
  for (int a=lane; a<NA; a+=64){
    float4 b = bb[a];
    float dx=b.x-tcx, dy=b.y-tcy;
    float dist = dx*dx + dy*dy;
    if (dist < d[KNN-1]){
      // statically-indexed bubble insert (ties: new elem (higher anchor) stays behind)
      d[KNN-1]=dist; id[KNN-1]=a;
      #pragma unroll
      for (int k=KNN-1;k>0;k--){
        bool sw = d[k] < d[k-1];
        float td = sw ? d[k-1] : d[k];  float tk = sw ? d[k]  : d[k-1];
        int   ti = sw ? id[k-1] : id[k]; int  tj = sw ? id[k] : id[k-1];
        d[k]=td; d[k-1]=tk; id[k]=ti; id[k-1]=tj;
      }
    }
  }
  // merge: 10 rounds of wave argmin over each lane's head (d[0]); shift-down pop
  for (int r=0;r<KNN;r++){
    float v  = d[0];
    int  anc = id[0];
    #pragma unroll
    for (int off=32; off>0; off>>=1){
      float v2 = __shfl_xor(v, off);
      int  a2 = __shfl_xor(anc, off);
      if (v2 < v || (v2==v && a2<anc)){ v=v2; anc=a2; }
    }
    if (anc == id[0] && v == d[0]){
      // this lane (first match on ties has same anc) pops its head
      #pragma unroll
      for (int k=0;k<KNN-1;k++){ d[k]=d[k+1]; id[k]=id[k+1]; }
      d[KNN-1]=FLT_MAX; id[KNN-1]=-1;
    }
    if (lane == 0) cand[(size_t)(img*NGT+g)*KNN + r] = anc;
  }
}

// one wave per (img,gt): argmin of cost over the image's 600 candidates
__global__ __launch_bounds__(256) void match_kernel(const float4* __restrict__ boxes,
                                                    const int* __restrict__ cand,
                                                    const float* __restrict__ gt,
                                                    const int* __restrict__ labels,
                                                    const float* __restrict__ p0,
                                                    const float* __restrict__ p1,
                                                    const float* __restrict__ p2,
                                                    int* __restrict__ matched){
  int wid  = threadIdx.x >> 6;
  int lane = threadIdx.x & 63;
  int pair = blockIdx.x*4 + wid;
  int img = pair / NGT, j = pair - img*NGT;
  const float* gb = gt + (size_t)(img*NGT + j)*4;
  float gx=gb[0], gy=gb[1], gz=gb[2], gw=gb[3];
  float a2 = fmaxf(gz-gx,0.f)*fmaxf(gw-gy,0.f);
  int lab = labels[img*NGT + j];

  const int* ci = cand + (size_t)img*NCAND;
  float best = FLT_MAX; int bslot = 1<<30; int banchor = -1;
  for (int c=lane; c<NCAND; c+=64){
    int a = ci[c];
    float4 b = boxes[(size_t)img*NA + a];
    float bx1=b.x-b.z*0.5f, by1=b.y-b.w*0.5f, bx2=b.x+b.z*0.5f, by2=b.y+b.w*0.5f;
    float a1 = fmaxf(bx2-bx1,0.f)*fmaxf(by2-by1,0.f);
    float ix1=fmaxf(bx1,gx), iy1=fmaxf(by1,gy);
    float ix2=fminf(bx2,gz), iy2=fminf(by2,gw);
    float inter = fmaxf(ix2-ix1,0.f)*fmaxf(iy2-iy1,0.f);
    float uni = a1 + a2 - inter + EPSF;
    float iou = fminf(fmaxf(inter/uni,0.f),1.f);
    float lg = anchor_base(p0,p1,p2,img,a)[4+lab];
    float cost = 0.5f*(1.f - sigm(lg)) + 6.f*(1.f - iou);
    if (cost < best){ best=cost; bslot=c; banchor=a; }  // c ascending per lane
  }
  #pragma unroll
  for (int off=32; off>0; off>>=1){
    float v2 = __shfl_xor(best, off);
    int  s2 = __shfl_xor(bslot, off);
    int  a2s= __shfl_xor(banchor, off);
    if (v2 < best || (v2==best && s2<bslot)){ best=v2; bslot=s2; banchor=a2s; }
  }
  if (lane == 0) matched[img*NGT + j] = banchor;
}

// one wave per image: ciou sum + dedup'd focal corrections
__global__ __launch_bounds__(64) void tail_kernel(const float4* __restrict__ boxes,
                                                  const int* __restrict__ matched_g,
                                                  const float* __restrict__ gt,
                                                  const int* __restrict__ labels,
                                                  const float* __restrict__ p0,
                                                  const float* __restrict__ p1,
                                                  const float* __restrict__ p2,
                                                  float* acc){
  int img = blockIdx.x;
  int tid = threadIdx.x;
  __shared__ int sm[NGT];
  __shared__ int sl[NGT];
  if (tid < NGT){ sm[tid] = matched_g[img*NGT + tid]; sl[tid] = labels[img*NGT + tid]; }
  __syncthreads();

  float local_box = 0.f, local_corr = 0.f;
  if (tid < NGT){
    int j = tid;
    int m = sm[j];
    float4 pb = boxes[(size_t)img*NA + m];
    float px1=pb.x-pb.z*0.5f, py1=pb.y-pb.w*0.5f, px2=pb.x+pb.z*0.5f, py2=pb.y+pb.w*0.5f;
    const float* gb = gt + (size_t)(img*NGT + j)*4;
    float gx=gb[0], gy=gb[1], gz=gb[2], gw=gb[3];
    float pw=fmaxf(px2-px1,EPSF), ph=fmaxf(py2-py1,EPSF);
    float tw=fmaxf(gz-gx,EPSF),  th=fmaxf(gw-gy,EPSF);
    float inter = fmaxf(fminf(px2,gz)-fmaxf(px1,gx),0.f)*fmaxf(fminf(py2,gw)-fmaxf(py1,gy),0.f);
    float uni = pw*ph + tw*th - inter + EPSF;
    float iou = inter/uni;
    float dcx = (px1+px2)*0.5f - (gx+gz)*0.5f;
    float dcy = (py1+py2)*0.5f - (gy+gw)*0.5f;
    float cd = dcx*dcx + dcy*dcy;
    float cw = fmaxf(px2,gz) - fminf(px1,gx);
    float ch = fmaxf(py2,gw) - fminf(py1,gy);
    float c2 = cw*cw + ch*ch + EPSF;
    float dv = atanf(tw/th) - atanf(pw/ph);
    float v  = (4.f/(PIF*PIF))*dv*dv;
    float alpha = v/(v - iou + 1.f + EPSF);
    float ciou = iou - cd/c2 - alpha*v;
    local_box = 1.f - ciou;

    int lab = sl[j];
    bool dup = false;
    for (int j2=0; j2<j; j2++)
      if (sm[j2]==m && sl[j2]==lab){ dup=true; break; }
    if (!dup){
      float x = anchor_base(p0,p1,p2,img,m)[4+lab];
      float s  = sigm(x);
      float sp_pos = fmaxf(-x,0.f)+log1pf(expf(-fabsf(x)));  // ce for tgt=1
      float sp_neg = fmaxf( x,0.f)+log1pf(expf(-fabsf(x)));  // ce for tgt=0
      local_corr = 0.25f*sp_pos*(1.f-s)*(1.f-s) - 0.75f*sp_neg*s*s;
    }
  }
  #pragma unroll
  for (int off=32; off>0; off>>=1){
    local_box  += __shfl_xor(local_box,  off);
    local_corr += __shfl_xor(local_corr, off);
  }
  if (tid==0){ atomicAdd(acc+0, local_box); atomicAdd(acc+2, local_corr); }
}

__device__ __forceinline__ float fbg(float x){
  float sp = fmaxf(x,0.f)+log1pf(expf(-fabsf(x)));
  float s  = 1.0f/(1.0f+expf(-x));
  return sp*s*s;
}

// fused background focal over all three tensors, float4-vectorized
__global__ __launch_bounds__(256) void focal_kernel(const float* __restrict__ p0,
                                                    const float* __restrict__ p1,
                                                    const float* __restrict__ p2,
                                                    float* acc){
  const unsigned nv0 = NB*6400u*84u/4u;
  const unsigned nv1 = NB*1600u*84u/4u;
  const unsigned nv2 = NB*400u*84u/4u;
  const unsigned total = nv0+nv1+nv2;
  __shared__ float sbuf[4];
  float sum = 0.f;
  unsigned stride = gridDim.x*blockDim.x;
  for (unsigned v = blockIdx.x*blockDim.x + threadIdx.x; v < total; v += stride){
    const float* p; unsigned s;
    if (v < nv0)           { p=p0; s = v*4u; }
    else if (v < nv0+nv1)  { p=p1; s = (v-nv0)*4u; }
    else                   { p=p2; s = (v-nv0-nv1)*4u; }
    if ((s % 84u) == 0u) continue;         // channels 0..3 = box channels
    float4 x4 = *(const float4*)(p + s);
    sum += fbg(x4.x) + fbg(x4.y) + fbg(x4.z) + fbg(x4.w);
  }
  sum *= 0.75f;
  #pragma unroll
  for (int off=32; off>0; off>>=1) sum += __shfl_xor(sum, off);
  int wid = threadIdx.x >> 6;
  if ((threadIdx.x & 63) == 0) sbuf[wid] = sum;
  __syncthreads();
  if (threadIdx.x == 0) atomicAdd(acc+1, sbuf[0]+sbuf[1]+sbuf[2]+sbuf[3]);
}

__global__ void finalize_kernel(const float* acc, float* out){
  out[0] = (7.5f*acc[0] + 0.5f*(acc[1]+acc[2])) / (60.f*16.f);
}

extern "C" void kernel_launch(void* const* d_in, const int* in_sizes, int n_in,
                              void* d_out, int out_size, void* d_ws, size_t ws_size,
                              hipStream_t stream){
  const float* p0 = (const float*)d_in[0];
  const float* p1 = (const float*)d_in[1];
  const float* p2 = (const float*)d_in[2];
  const float* gt = (const float*)d_in[3];
  const int* labels = (const int*)d_in[4];
  float* out = (float*)d_out;

  // workspace layout
  float*  acc     = (float*)d_ws;                                   // 16 floats
  float4* boxes   = (float4*)((char*)d_ws + 64);                    // 2.15 MB
  int*    cand    = (int*)((char*)d_ws + 64 + (size_t)NB*NA*sizeof(float4));
  int*    matched = (int*)((char*)cand + (size_t)NB*NCAND*sizeof(int));

  decode_kernel<<<(NB*NA + 255)/256, 256, 0, stream>>>(p0, p1, p2, boxes, acc);
  topk_kernel<<<NB*NGT/4, 256, 0, stream>>>(boxes, gt, cand);
  match_kernel<<<NB*NGT/4, 256, 0, stream>>>(boxes, cand, gt, labels, p0, p1, p2, matched);
  focal_kernel<<<2048, 256, 0, stream>>>(p0, p1, p2, acc);
  tail_kernel<<<NB, 64, 0, stream>>>(boxes, matched, gt, labels, p0, p1, p2, acc);
  finalize_kernel<<<1, 1, 0, stream>>>(acc, out);
}

// Round 3
// 178.021 us; speedup vs baseline: 1.7075x; 1.1643x over previous
//
#include <hip/hip_runtime.h>
#include <cfloat>
#include <math.h>

#define NB   16
#define NGT  60
#define NA   8400
#define KNN  10
#define NCAND (NGT*KNN)   // 600
#define EPSF 1e-7f
#define PIF  3.14159265358979f
#define FOCAL_BLOCKS 2048

__device__ __forceinline__ float sigm(float x){ return 1.0f/(1.0f+expf(-x)); }
__device__ __forceinline__ float softplusf_(float x){ return fmaxf(x,0.f)+log1pf(expf(-fabsf(x))); }

__device__ __forceinline__ const float* anchor_base(const float* p0,const float* p1,const float* p2,int img,int a){
  if (a < 6400) return p0 + (size_t)(img*6400 + a)*84;
  if (a < 8000) return p1 + (size_t)(img*1600 + (a-6400))*84;
  return p2 + (size_t)(img*400 + (a-8000))*84;
}

__device__ __forceinline__ float fbg(float x){
  float sp = fmaxf(x,0.f)+log1pf(expf(-fabsf(x)));
  float s  = 1.0f/(1.0f+expf(-x));
  return sp*s*s;
}

// single streaming pass over all three tensors: background focal sum (per-block
// partials, no atomics) + decode of the box channels (s%84==0 lanes)
__global__ __launch_bounds__(256) void fused_decode_focal(const float* __restrict__ p0,
                                                          const float* __restrict__ p1,
                                                          const float* __restrict__ p2,
                                                          float4* __restrict__ boxes,
                                                          float* __restrict__ fsum){
  const unsigned nv0 = NB*6400u*84u/4u;
  const unsigned nv1 = NB*1600u*84u/4u;
  const unsigned nv2 = NB*400u*84u/4u;
  const unsigned total = nv0+nv1+nv2;
  __shared__ float sbuf[4];
  float sum = 0.f;
  unsigned stride = gridDim.x*blockDim.x;
  for (unsigned v = blockIdx.x*blockDim.x + threadIdx.x; v < total; v += stride){
    const float* p; unsigned s; int S; float stf; int base;
    if (v < nv0)          { p=p0; s = v*4u;            S=80; stf= 8.f; base=0; }
    else if (v < nv0+nv1) { p=p1; s = (v-nv0)*4u;      S=40; stf=16.f; base=6400; }
    else                  { p=p2; s = (v-nv0-nv1)*4u;  S=20; stf=32.f; base=8000; }
    float4 x4 = *(const float4*)(p + s);
    if ((s % 84u) == 0u){
      unsigned row = s / 84u;                 // row within this tensor
      int img   = row / (unsigned)(S*S);
      int local = row - img*(S*S);
      int i = local / S, j = local - i*S;
      float px = (sigm(x4.x)*2.f - 0.5f + (float)j)*stf;
      float py = (sigm(x4.y)*2.f - 0.5f + (float)i)*stf;
      float pw = softplusf_(x4.z)*stf;
      float ph = softplusf_(x4.w)*stf;
      boxes[(size_t)img*NA + base + local] = make_float4(px,py,pw,ph);
    } else {
      sum += fbg(x4.x) + fbg(x4.y) + fbg(x4.z) + fbg(x4.w);
    }
  }
  sum *= 0.75f;
  #pragma unroll
  for (int off=32; off>0; off>>=1) sum += __shfl_xor(sum, off);
  int wid = threadIdx.x >> 6;
  if ((threadIdx.x & 63) == 0) sbuf[wid] = sum;
  __syncthreads();
  if (threadIdx.x == 0) fsum[blockIdx.x] = sbuf[0]+sbuf[1]+sbuf[2]+sbuf[3];
}

// one BLOCK (4 waves) per (img,gt): each wave top-10 over a 2100-anchor chunk,
// wave 0 merges 40 -> 10
__global__ __launch_bounds__(256) void topk_kernel(const float4* __restrict__ boxes,
                                                   const float* __restrict__ gt,
                                                   int* __restrict__ cand){
  int wid  = threadIdx.x >> 6;
  int lane = threadIdx.x & 63;
  int pair = blockIdx.x;                  // 0 .. 959
  int img = pair / NGT, g = pair - img*NGT;
  const float* gb = gt + (size_t)(img*NGT + g)*4;
  float tcx = (gb[0]+gb[2])*0.5f, tcy = (gb[1]+gb[3])*0.5f;

  float d[KNN]; int id[KNN];
  #pragma unroll
  for (int k=0;k<KNN;k++){ d[k]=FLT_MAX; id[k]=-1; }

  const float4* bb = boxes + (size_t)img*NA;
  int start = wid*2100, end = start+2100;
  for (int a = start+lane; a < end; a += 64){
    float4 b = bb[a];
    float dx=b.x-tcx, dy=b.y-tcy;
    float dist = dx*dx + dy*dy;
    if (dist < d[KNN-1]){
      d[KNN-1]=dist; id[KNN-1]=a;
      #pragma unroll
      for (int k=KNN-1;k>0;k--){
        bool sw = d[k] < d[k-1];
        float td = sw ? d[k-1] : d[k];  float tk = sw ? d[k]  : d[k-1];
        int   ti = sw ? id[k-1] : id[k]; int  tj = sw ? id[k] : id[k-1];
        d[k]=td; d[k-1]=tk; id[k]=ti; id[k-1]=tj;
      }
    }
  }

  __shared__ float md[40];
  __shared__ int   ma[40];
  // per-wave merge: 10 rounds of wave argmin over heads, shift-down pop
  for (int r=0;r<KNN;r++){
    float v  = d[0];
    int  anc = id[0];
    #pragma unroll
    for (int off=32; off>0; off>>=1){
      float v2 = __shfl_xor(v, off);
      int  a2 = __shfl_xor(anc, off);
      if (v2 < v || (v2==v && a2<anc)){ v=v2; anc=a2; }
    }
    if (anc == id[0] && v == d[0]){
      #pragma unroll
      for (int k=0;k<KNN-1;k++){ d[k]=d[k+1]; id[k]=id[k+1]; }
      d[KNN-1]=FLT_MAX; id[KNN-1]=-1;
    }
    if (lane == 0){ md[wid*KNN + r] = v; ma[wid*KNN + r] = anc; }
  }
  __syncthreads();
  if (wid == 0){
    float dv = (lane < 40) ? md[lane] : FLT_MAX;
    int   av = (lane < 40) ? ma[lane] : 0x7fffffff;
    for (int r=0;r<KNN;r++){
      float v  = dv;
      int  anc = av;
      #pragma unroll
      for (int off=32; off>0; off>>=1){
        float v2 = __shfl_xor(v, off);
        int  a2 = __shfl_xor(anc, off);
        if (v2 < v || (v2==v && a2<anc)){ v=v2; anc=a2; }
      }
      if (av == anc){ dv = FLT_MAX; av = 0x7fffffff; }  // anchor ids unique -> exact pop
      if (lane == 0) cand[(size_t)pair*KNN + r] = anc;
    }
  }
}

// one wave per (img,gt): argmin of cost over the image's 600 candidates
__global__ __launch_bounds__(256) void match_kernel(const float4* __restrict__ boxes,
                                                    const int* __restrict__ cand,
                                                    const float* __restrict__ gt,
                                                    const int* __restrict__ labels,
                                                    const float* __restrict__ p0,
                                                    const float* __restrict__ p1,
                                                    const float* __restrict__ p2,
                                                    int* __restrict__ matched){
  int wid  = threadIdx.x >> 6;
  int lane = threadIdx.x & 63;
  int pair = blockIdx.x*4 + wid;
  int img = pair / NGT, j = pair - img*NGT;
  const float* gb = gt + (size_t)(img*NGT + j)*4;
  float gx=gb[0], gy=gb[1], gz=gb[2], gw=gb[3];
  float a2 = fmaxf(gz-gx,0.f)*fmaxf(gw-gy,0.f);
  int lab = labels[img*NGT + j];

  const int* ci = cand + (size_t)img*NCAND;
  float best = FLT_MAX; int bslot = 1<<30; int banchor = -1;
  for (int c=lane; c<NCAND; c+=64){
    int a = ci[c];
    float4 b = boxes[(size_t)img*NA + a];
    float bx1=b.x-b.z*0.5f, by1=b.y-b.w*0.5f, bx2=b.x+b.z*0.5f, by2=b.y+b.w*0.5f;
    float a1 = fmaxf(bx2-bx1,0.f)*fmaxf(by2-by1,0.f);
    float ix1=fmaxf(bx1,gx), iy1=fmaxf(by1,gy);
    float ix2=fminf(bx2,gz), iy2=fminf(by2,gw);
    float inter = fmaxf(ix2-ix1,0.f)*fmaxf(iy2-iy1,0.f);
    float uni = a1 + a2 - inter + EPSF;
    float iou = fminf(fmaxf(inter/uni,0.f),1.f);
    float lg = anchor_base(p0,p1,p2,img,a)[4+lab];
    float cost = 0.5f*(1.f - sigm(lg)) + 6.f*(1.f - iou);
    if (cost < best){ best=cost; bslot=c; banchor=a; }  // c ascending per lane
  }
  #pragma unroll
  for (int off=32; off>0; off>>=1){
    float v2 = __shfl_xor(best, off);
    int  s2 = __shfl_xor(bslot, off);
    int  a2s= __shfl_xor(banchor, off);
    if (v2 < best || (v2==best && s2<bslot)){ best=v2; bslot=s2; banchor=a2s; }
  }
  if (lane == 0) matched[img*NGT + j] = banchor;
}

// single block, 16 waves (one image each): ciou + dedup'd corrections + focal
// partial reduction + final scalar
__global__ __launch_bounds__(1024) void tail_kernel(const float4* __restrict__ boxes,
                                                    const int* __restrict__ matched_g,
                                                    const float* __restrict__ gt,
                                                    const int* __restrict__ labels,
                                                    const float* __restrict__ p0,
                                                    const float* __restrict__ p1,
                                                    const float* __restrict__ p2,
                                                    const float* __restrict__ fsum,
                                                    float* __restrict__ out){
  int tid = threadIdx.x;
  int wid = tid >> 6;        // image
  int lane = tid & 63;
  __shared__ int sm[NB][NGT];
  __shared__ int sl[NB][NGT];
  __shared__ float wb[NB], wc[NB], wf[NB];
  if (lane < NGT){
    sm[wid][lane] = matched_g[wid*NGT + lane];
    sl[wid][lane] = labels[wid*NGT + lane];
  }
  __syncthreads();

  int img = wid;
  float local_box = 0.f, local_corr = 0.f;
  if (lane < NGT){
    int j = lane;
    int m = sm[img][j];
    float4 pb = boxes[(size_t)img*NA + m];
    float px1=pb.x-pb.z*0.5f, py1=pb.y-pb.w*0.5f, px2=pb.x+pb.z*0.5f, py2=pb.y+pb.w*0.5f;
    const float* gb = gt + (size_t)(img*NGT + j)*4;
    float gx=gb[0], gy=gb[1], gz=gb[2], gw=gb[3];
    float pw=fmaxf(px2-px1,EPSF), ph=fmaxf(py2-py1,EPSF);
    float tw=fmaxf(gz-gx,EPSF),  th=fmaxf(gw-gy,EPSF);
    float inter = fmaxf(fminf(px2,gz)-fmaxf(px1,gx),0.f)*fmaxf(fminf(py2,gw)-fmaxf(py1,gy),0.f);
    float uni = pw*ph + tw*th - inter + EPSF;
    float iou = inter/uni;
    float dcx = (px1+px2)*0.5f - (gx+gz)*0.5f;
    float dcy = (py1+py2)*0.5f - (gy+gw)*0.5f;
    float cd = dcx*dcx + dcy*dcy;
    float cw = fmaxf(px2,gz) - fminf(px1,gx);
    float ch = fmaxf(py2,gw) - fminf(py1,gy);
    float c2 = cw*cw + ch*ch + EPSF;
    float dv = atanf(tw/th) - atanf(pw/ph);
    float v  = (4.f/(PIF*PIF))*dv*dv;
    float alpha = v/(v - iou + 1.f + EPSF);
    float ciou = iou - cd/c2 - alpha*v;
    local_box = 1.f - ciou;

    int lab = sl[img][j];
    bool dup = false;
    for (int j2=0; j2<j; j2++)
      if (sm[img][j2]==m && sl[img][j2]==lab){ dup=true; break; }
    if (!dup){
      float x = anchor_base(p0,p1,p2,img,m)[4+lab];
      float s  = sigm(x);
      float sp_pos = fmaxf(-x,0.f)+log1pf(expf(-fabsf(x)));  // ce for tgt=1
      float sp_neg = fmaxf( x,0.f)+log1pf(expf(-fabsf(x)));  // ce for tgt=0
      local_corr = 0.25f*sp_pos*(1.f-s)*(1.f-s) - 0.75f*sp_neg*s*s;
    }
  }
  float local_f = fsum[tid] + fsum[tid + 1024];
  #pragma unroll
  for (int off=32; off>0; off>>=1){
    local_box  += __shfl_xor(local_box,  off);
    local_corr += __shfl_xor(local_corr, off);
    local_f    += __shfl_xor(local_f,    off);
  }
  if (lane == 0){ wb[wid]=local_box; wc[wid]=local_corr; wf[wid]=local_f; }
  __syncthreads();
  if (tid == 0){
    float sb=0.f, sc=0.f, sf=0.f;
    #pragma unroll
    for (int k=0;k<NB;k++){ sb+=wb[k]; sc+=wc[k]; sf+=wf[k]; }
    out[0] = (7.5f*sb + 0.5f*(sf + sc)) / (60.f*16.f);
  }
}

extern "C" void kernel_launch(void* const* d_in, const int* in_sizes, int n_in,
                              void* d_out, int out_size, void* d_ws, size_t ws_size,
                              hipStream_t stream){
  const float* p0 = (const float*)d_in[0];
  const float* p1 = (const float*)d_in[1];
  const float* p2 = (const float*)d_in[2];
  const float* gt = (const float*)d_in[3];
  const int* labels = (const int*)d_in[4];
  float* out = (float*)d_out;

  // workspace layout
  float4* boxes   = (float4*)d_ws;                                       // 2.15 MB
  int*    cand    = (int*)((char*)d_ws + (size_t)NB*NA*sizeof(float4));  // 38.4 KB
  int*    matched = (int*)((char*)cand + (size_t)NB*NCAND*sizeof(int));  // 3.8 KB
  float*  fsum    = (float*)((char*)matched + (size_t)NB*NGT*sizeof(int)); // 8 KB

  fused_decode_focal<<<FOCAL_BLOCKS, 256, 0, stream>>>(p0, p1, p2, boxes, fsum);
  topk_kernel<<<NB*NGT, 256, 0, stream>>>(boxes, gt, cand);
  match_kernel<<<NB*NGT/4, 256, 0, stream>>>(boxes, cand, gt, labels, p0, p1, p2, matched);
  tail_kernel<<<1, 1024, 0, stream>>>(boxes, matched, gt, labels, p0, p1, p2, fsum, out);
}

// Round 4
// 101.188 us; speedup vs baseline: 3.0041x; 1.7593x over previous
//
#include <hip/hip_runtime.h>
#include <cfloat>
#include <math.h>

#define NB   16
#define NGT  60
#define NA   8400
#define KNN  10
#define NCAND (NGT*KNN)   // 600
#define EPSF 1e-7f
#define PIF  3.14159265358979f
#define FOCAL_BLOCKS 2048

__device__ __forceinline__ float sigm(float x){ return 1.0f/(1.0f+expf(-x)); }
__device__ __forceinline__ float softplusf_(float x){ return fmaxf(x,0.f)+log1pf(expf(-fabsf(x))); }

__device__ __forceinline__ const float* anchor_base(const float* p0,const float* p1,const float* p2,int img,int a){
  if (a < 6400) return p0 + (size_t)(img*6400 + a)*84;
  if (a < 8000) return p1 + (size_t)(img*1600 + (a-6400))*84;
  return p2 + (size_t)(img*400 + (a-8000))*84;
}

__device__ __forceinline__ float fbg(float x){
  float sp = fmaxf(x,0.f)+log1pf(expf(-fabsf(x)));
  float s  = 1.0f/(1.0f+expf(-x));
  return sp*s*s;
}

// single streaming pass: background focal partials + decode of box channels
__global__ __launch_bounds__(256) void fused_decode_focal(const float* __restrict__ p0,
                                                          const float* __restrict__ p1,
                                                          const float* __restrict__ p2,
                                                          float4* __restrict__ boxes,
                                                          float* __restrict__ fsum){
  const unsigned nv0 = NB*6400u*84u/4u;
  const unsigned nv1 = NB*1600u*84u/4u;
  const unsigned nv2 = NB*400u*84u/4u;
  const unsigned total = nv0+nv1+nv2;
  __shared__ float sbuf[4];
  float sum = 0.f;
  unsigned stride = gridDim.x*blockDim.x;
  for (unsigned v = blockIdx.x*blockDim.x + threadIdx.x; v < total; v += stride){
    const float* p; unsigned s; int S; float stf; int base;
    if (v < nv0)          { p=p0; s = v*4u;            S=80; stf= 8.f; base=0; }
    else if (v < nv0+nv1) { p=p1; s = (v-nv0)*4u;      S=40; stf=16.f; base=6400; }
    else                  { p=p2; s = (v-nv0-nv1)*4u;  S=20; stf=32.f; base=8000; }
    float4 x4 = *(const float4*)(p + s);
    if ((s % 84u) == 0u){
      unsigned row = s / 84u;
      int img   = row / (unsigned)(S*S);
      int local = row - img*(S*S);
      int i = local / S, j = local - i*S;
      float px = (sigm(x4.x)*2.f - 0.5f + (float)j)*stf;
      float py = (sigm(x4.y)*2.f - 0.5f + (float)i)*stf;
      float pw = softplusf_(x4.z)*stf;
      float ph = softplusf_(x4.w)*stf;
      boxes[(size_t)img*NA + base + local] = make_float4(px,py,pw,ph);
    } else {
      sum += fbg(x4.x) + fbg(x4.y) + fbg(x4.z) + fbg(x4.w);
    }
  }
  sum *= 0.75f;
  #pragma unroll
  for (int off=32; off>0; off>>=1) sum += __shfl_xor(sum, off);
  int wid = threadIdx.x >> 6;
  if ((threadIdx.x & 63) == 0) sbuf[wid] = sum;
  __syncthreads();
  if (threadIdx.x == 0) fsum[blockIdx.x] = sbuf[0]+sbuf[1]+sbuf[2]+sbuf[3];
}

// one wave per (img,gt), 4 waves/block. Exact top-10 from pruned windows:
// 13x13 on level0 + 7x7 on level1 + 5x5 on level2 = 243 candidate anchors.
// Proof of exactness: the 16 level-0 anchors in the 4x4 block around the GT
// center all have dist^2 <= 28^2+28^2 = 1568 (anchor center within
// ((j-0.5)s,(j+1.5)s)), so d10 <= 1568; any anchor outside the windows has
// min-possible dist^2 > 1568 and cannot enter (or tie into) the top-10.
__global__ __launch_bounds__(256) void topk_kernel(const float4* __restrict__ boxes,
                                                   const float* __restrict__ gt,
                                                   int* __restrict__ cand){
  int wid  = threadIdx.x >> 6;
  int lane = threadIdx.x & 63;
  int pair = blockIdx.x*4 + wid;          // 0..959
  int img = pair / NGT, g = pair - img*NGT;
  const float* gb = gt + (size_t)(img*NGT + g)*4;
  float tcx = (gb[0]+gb[2])*0.5f, tcy = (gb[1]+gb[3])*0.5f;

  int jx0 = (int)(tcx * 0.125f),   iy0 = (int)(tcy * 0.125f);    // level0 cell
  int jx1 = (int)(tcx * 0.0625f),  iy1 = (int)(tcy * 0.0625f);   // level1
  int jx2 = (int)(tcx * 0.03125f), iy2 = (int)(tcy * 0.03125f);  // level2

  const float4* bb = boxes + (size_t)img*NA;

  float d0=FLT_MAX,d1=FLT_MAX,d2=FLT_MAX,d3=FLT_MAX;
  int   a0,a1,a2,a3;
  #pragma unroll
  for (int s=0; s<4; s++){
    int c = lane + 64*s;
    float dd = FLT_MAX; int aa = 9000000 + c;   // unique fake id
    int i, j, S, base, valid = 1;
    if (c < 169)      { int r=c/13,  q=c-13*r;          i=iy0-6+r; j=jx0-6+q; S=80; base=0; }
    else if (c < 218) { int t=c-169; int r=t/7, q=t-7*r; i=iy1-3+r; j=jx1-3+q; S=40; base=6400; }
    else if (c < 243) { int t=c-218; int r=t/5, q=t-5*r; i=iy2-2+r; j=jx2-2+q; S=20; base=8000; }
    else { valid = 0; i=j=0; S=1; base=0; }
    if (valid && i>=0 && i<S && j>=0 && j<S){
      int anchor = base + i*S + j;
      float4 b = bb[anchor];
      float dx=b.x-tcx, dy=b.y-tcy;
      dd = dx*dx + dy*dy;
      aa = anchor;
    }
    if (s==0){ d0=dd; a0=aa; } else if (s==1){ d1=dd; a1=aa; }
    else if (s==2){ d2=dd; a2=aa; } else { d3=dd; a3=aa; }
  }

  for (int r=0; r<KNN; r++){
    float v = d0; int anc = a0;
    if (d1 < v || (d1==v && a1<anc)){ v=d1; anc=a1; }
    if (d2 < v || (d2==v && a2<anc)){ v=d2; anc=a2; }
    if (d3 < v || (d3==v && a3<anc)){ v=d3; anc=a3; }
    #pragma unroll
    for (int off=32; off>0; off>>=1){
      float v2 = __shfl_xor(v, off);
      int  A2 = __shfl_xor(anc, off);
      if (v2 < v || (v2==v && A2<anc)){ v=v2; anc=A2; }
    }
    if (a0==anc) d0=FLT_MAX;
    if (a1==anc) d1=FLT_MAX;
    if (a2==anc) d2=FLT_MAX;
    if (a3==anc) d3=FLT_MAX;
    if (lane == 0) cand[(size_t)pair*KNN + r] = anc;
  }
}

// one BLOCK per (img,gt): 256 threads scan 600 candidates (2-3 each)
__global__ __launch_bounds__(256) void match_kernel(const float4* __restrict__ boxes,
                                                    const int* __restrict__ cand,
                                                    const float* __restrict__ gt,
                                                    const int* __restrict__ labels,
                                                    const float* __restrict__ p0,
                                                    const float* __restrict__ p1,
                                                    const float* __restrict__ p2,
                                                    int* __restrict__ matched){
  int pair = blockIdx.x;
  int img = pair / NGT, j = pair - img*NGT;
  int tid = threadIdx.x;
  int wid = tid >> 6, lane = tid & 63;
  const float* gb = gt + (size_t)(img*NGT + j)*4;
  float gx=gb[0], gy=gb[1], gz=gb[2], gw=gb[3];
  float a2 = fmaxf(gz-gx,0.f)*fmaxf(gw-gy,0.f);
  int lab = labels[img*NGT + j];

  const int* ci = cand + (size_t)img*NCAND;
  float best = FLT_MAX; int bslot = 1<<30; int banchor = -1;
  for (int c=tid; c<NCAND; c+=256){
    int a = ci[c];
    float4 b = boxes[(size_t)img*NA + a];
    float bx1=b.x-b.z*0.5f, by1=b.y-b.w*0.5f, bx2=b.x+b.z*0.5f, by2=b.y+b.w*0.5f;
    float a1 = fmaxf(bx2-bx1,0.f)*fmaxf(by2-by1,0.f);
    float ix1=fmaxf(bx1,gx), iy1=fmaxf(by1,gy);
    float ix2=fminf(bx2,gz), iy2=fminf(by2,gw);
    float inter = fmaxf(ix2-ix1,0.f)*fmaxf(iy2-iy1,0.f);
    float uni = a1 + a2 - inter + EPSF;
    float iou = fminf(fmaxf(inter/uni,0.f),1.f);
    float lg = anchor_base(p0,p1,p2,img,a)[4+lab];
    float cost = 0.5f*(1.f - sigm(lg)) + 6.f*(1.f - iou);
    if (cost < best){ best=cost; bslot=c; banchor=a; }
  }
  #pragma unroll
  for (int off=32; off>0; off>>=1){
    float v2 = __shfl_xor(best, off);
    int  s2 = __shfl_xor(bslot, off);
    int  a2s= __shfl_xor(banchor, off);
    if (v2 < best || (v2==best && s2<bslot)){ best=v2; bslot=s2; banchor=a2s; }
  }
  __shared__ float bc[4]; __shared__ int bs[4], ba[4];
  if (lane == 0){ bc[wid]=best; bs[wid]=bslot; ba[wid]=banchor; }
  __syncthreads();
  if (tid == 0){
    float v=bc[0]; int s=bs[0]; int a=ba[0];
    #pragma unroll
    for (int k=1;k<4;k++){
      if (bc[k] < v || (bc[k]==v && bs[k]<s)){ v=bc[k]; s=bs[k]; a=ba[k]; }
    }
    matched[img*NGT + j] = a;
  }
}

// single block, 16 waves (one image each): ciou + dedup'd corrections + focal
// partial reduction + final scalar
__global__ __launch_bounds__(1024) void tail_kernel(const float4* __restrict__ boxes,
                                                    const int* __restrict__ matched_g,
                                                    const float* __restrict__ gt,
                                                    const int* __restrict__ labels,
                                                    const float* __restrict__ p0,
                                                    const float* __restrict__ p1,
                                                    const float* __restrict__ p2,
                                                    const float* __restrict__ fsum,
                                                    float* __restrict__ out){
  int tid = threadIdx.x;
  int wid = tid >> 6;        // image
  int lane = tid & 63;
  __shared__ int sm[NB][NGT];
  __shared__ int sl[NB][NGT];
  __shared__ float wb[NB], wc[NB], wf[NB];
  if (lane < NGT){
    sm[wid][lane] = matched_g[wid*NGT + lane];
    sl[wid][lane] = labels[wid*NGT + lane];
  }
  __syncthreads();

  int img = wid;
  float local_box = 0.f, local_corr = 0.f;
  if (lane < NGT){
    int j = lane;
    int m = sm[img][j];
    float4 pb = boxes[(size_t)img*NA + m];
    float px1=pb.x-pb.z*0.5f, py1=pb.y-pb.w*0.5f, px2=pb.x+pb.z*0.5f, py2=pb.y+pb.w*0.5f;
    const float* gb = gt + (size_t)(img*NGT + j)*4;
    float gx=gb[0], gy=gb[1], gz=gb[2], gw=gb[3];
    float pw=fmaxf(px2-px1,EPSF), ph=fmaxf(py2-py1,EPSF);
    float tw=fmaxf(gz-gx,EPSF),  th=fmaxf(gw-gy,EPSF);
    float inter = fmaxf(fminf(px2,gz)-fmaxf(px1,gx),0.f)*fmaxf(fminf(py2,gw)-fmaxf(py1,gy),0.f);
    float uni = pw*ph + tw*th - inter + EPSF;
    float iou = inter/uni;
    float dcx = (px1+px2)*0.5f - (gx+gz)*0.5f;
    float dcy = (py1+py2)*0.5f - (gy+gw)*0.5f;
    float cd = dcx*dcx + dcy*dcy;
    float cw = fmaxf(px2,gz) - fminf(px1,gx);
    float ch = fmaxf(py2,gw) - fminf(py1,gy);
    float c2 = cw*cw + ch*ch + EPSF;
    float dv = atanf(tw/th) - atanf(pw/ph);
    float v  = (4.f/(PIF*PIF))*dv*dv;
    float alpha = v/(v - iou + 1.f + EPSF);
    float ciou = iou - cd/c2 - alpha*v;
    local_box = 1.f - ciou;

    int lab = sl[img][j];
    bool dup = false;
    for (int j2=0; j2<j; j2++)
      if (sm[img][j2]==m && sl[img][j2]==lab){ dup=true; break; }
    if (!dup){
      float x = anchor_base(p0,p1,p2,img,m)[4+lab];
      float s  = sigm(x);
      float sp_pos = fmaxf(-x,0.f)+log1pf(expf(-fabsf(x)));  // ce for tgt=1
      float sp_neg = fmaxf( x,0.f)+log1pf(expf(-fabsf(x)));  // ce for tgt=0
      local_corr = 0.25f*sp_pos*(1.f-s)*(1.f-s) - 0.75f*sp_neg*s*s;
    }
  }
  float local_f = fsum[tid] + fsum[tid + 1024];
  #pragma unroll
  for (int off=32; off>0; off>>=1){
    local_box  += __shfl_xor(local_box,  off);
    local_corr += __shfl_xor(local_corr, off);
    local_f    += __shfl_xor(local_f,    off);
  }
  if (lane == 0){ wb[wid]=local_box; wc[wid]=local_corr; wf[wid]=local_f; }
  __syncthreads();
  if (tid == 0){
    float sb=0.f, sc=0.f, sf=0.f;
    #pragma unroll
    for (int k=0;k<NB;k++){ sb+=wb[k]; sc+=wc[k]; sf+=wf[k]; }
    out[0] = (7.5f*sb + 0.5f*(sf + sc)) / (60.f*16.f);
  }
}

extern "C" void kernel_launch(void* const* d_in, const int* in_sizes, int n_in,
                              void* d_out, int out_size, void* d_ws, size_t ws_size,
                              hipStream_t stream){
  const float* p0 = (const float*)d_in[0];
  const float* p1 = (const float*)d_in[1];
  const float* p2 = (const float*)d_in[2];
  const float* gt = (const float*)d_in[3];
  const int* labels = (const int*)d_in[4];
  float* out = (float*)d_out;

  float4* boxes   = (float4*)d_ws;                                       // 2.15 MB
  int*    cand    = (int*)((char*)d_ws + (size_t)NB*NA*sizeof(float4));
  int*    matched = (int*)((char*)cand + (size_t)NB*NCAND*sizeof(int));
  float*  fsum    = (float*)((char*)matched + (size_t)NB*NGT*sizeof(int));

  fused_decode_focal<<<FOCAL_BLOCKS, 256, 0, stream>>>(p0, p1, p2, boxes, fsum);
  topk_kernel<<<NB*NGT/4, 256, 0, stream>>>(boxes, gt, cand);
  match_kernel<<<NB*NGT, 256, 0, stream>>>(boxes, cand, gt, labels, p0, p1, p2, matched);
  tail_kernel<<<1, 1024, 0, stream>>>(boxes, matched, gt, labels, p0, p1, p2, fsum, out);
}

// Round 5
// 47.684 us; speedup vs baseline: 6.3748x; 2.1221x over previous
//
#include <hip/hip_runtime.h>
#include <cfloat>
#include <math.h>

#define NB   16
#define NGT  60
#define NA   8400
#define KNN  10
#define NCAND (NGT*KNN)   // 600
#define EPSF 1e-7f
#define PIF  3.14159265358979f
#define FOCAL_BLOCKS 2048

#define LOG2E 1.44269504088896341f
#define LN2   0.69314718055994531f

// fast native-instruction math (v_exp_f32 / v_log_f32 / v_rcp_f32)
__device__ __forceinline__ float fexp2(float x){ return __builtin_amdgcn_exp2f(x); }
__device__ __forceinline__ float flog2(float x){ return __builtin_amdgcn_logf(x); }
__device__ __forceinline__ float frcp (float x){ return __builtin_amdgcn_rcpf(x); }

// sigmoid: 1/(1+e^-x); x<<0 -> exp2(+big)=inf -> rcp(inf)=0 (correct limit)
__device__ __forceinline__ float fsigm(float x){
  return frcp(1.0f + fexp2(-x*LOG2E));
}
// softplus: max(x,0) + ln(1+e^-|x|)   (u in (0,1], no overflow)
__device__ __forceinline__ float fsoftplus(float x){
  float u = fexp2(-fabsf(x)*LOG2E);
  return fmaxf(x,0.f) + LN2*flog2(1.0f + u);
}
// fbg = softplus(x)*sigmoid(x)^2 = (x + ln(1+u)) / (1+u)^2,  u = e^-x
__device__ __forceinline__ float fbg(float x){
  float u = fexp2(fminf(-x*LOG2E, 126.0f));   // clamp avoids inf*0
  float t = frcp(1.0f + u);
  return (x + LN2*flog2(1.0f + u)) * t * t;
}

// per-level body with compile-time dims: all int divs become magic-muls
template<int S, int BASE, int STRIDE_I>
__device__ __forceinline__ void do_vec(const float* __restrict__ p, unsigned vloc,
                                       float4* __restrict__ boxes, float& sum){
  unsigned s = vloc*4u;
  float4 x4 = *(const float4*)(p + s);
  if ((s % 84u) == 0u){
    unsigned row   = s / 84u;
    unsigned img   = row / (unsigned)(S*S);
    unsigned local = row - img*(unsigned)(S*S);
    unsigned i = local / (unsigned)S, j = local - i*(unsigned)S;
    const float stf = (float)STRIDE_I;
    float px = (fsigm(x4.x)*2.f - 0.5f + (float)j)*stf;
    float py = (fsigm(x4.y)*2.f - 0.5f + (float)i)*stf;
    float pw = fsoftplus(x4.z)*stf;
    float ph = fsoftplus(x4.w)*stf;
    boxes[(size_t)img*NA + BASE + local] = make_float4(px,py,pw,ph);
  } else {
    sum += fbg(x4.x) + fbg(x4.y) + fbg(x4.z) + fbg(x4.w);
  }
}

// single streaming pass: background focal partials + decode of box channels
__global__ __launch_bounds__(256) void fused_decode_focal(const float* __restrict__ p0,
                                                          const float* __restrict__ p1,
                                                          const float* __restrict__ p2,
                                                          float4* __restrict__ boxes,
                                                          float* __restrict__ fsum){
  const unsigned nv0 = NB*6400u*84u/4u;
  const unsigned nv1 = NB*1600u*84u/4u;
  const unsigned nv2 = NB*400u*84u/4u;
  const unsigned total = nv0+nv1+nv2;
  __shared__ float sbuf[4];
  float sum = 0.f;
  unsigned stride = gridDim.x*blockDim.x;
  for (unsigned v = blockIdx.x*blockDim.x + threadIdx.x; v < total; v += stride){
    if (v < nv0)          do_vec<80,    0,  8>(p0, v,          boxes, sum);
    else if (v < nv0+nv1) do_vec<40, 6400, 16>(p1, v-nv0,      boxes, sum);
    else                  do_vec<20, 8000, 32>(p2, v-nv0-nv1,  boxes, sum);
  }
  sum *= 0.75f;
  #pragma unroll
  for (int off=32; off>0; off>>=1) sum += __shfl_xor(sum, off);
  int wid = threadIdx.x >> 6;
  if ((threadIdx.x & 63) == 0) sbuf[wid] = sum;
  __syncthreads();
  if (threadIdx.x == 0) fsum[blockIdx.x] = sbuf[0]+sbuf[1]+sbuf[2]+sbuf[3];
}

__device__ __forceinline__ const float* anchor_base(const float* p0,const float* p1,const float* p2,int img,int a){
  if (a < 6400) return p0 + (size_t)(img*6400 + a)*84;
  if (a < 8000) return p1 + (size_t)(img*1600 + (a-6400))*84;
  return p2 + (size_t)(img*400 + (a-8000))*84;
}

// one wave per (img,gt), 4 waves/block. Exact top-10 from pruned windows:
// 13x13 (L0) + 7x7 (L1) + 5x5 (L2) = 243 candidates. d10 <= 1568 provably;
// anything outside the windows has min-possible dist^2 > 1568.
__global__ __launch_bounds__(256) void topk_kernel(const float4* __restrict__ boxes,
                                                   const float* __restrict__ gt,
                                                   int* __restrict__ cand){
  int wid  = threadIdx.x >> 6;
  int lane = threadIdx.x & 63;
  int pair = blockIdx.x*4 + wid;          // 0..959
  int img = pair / NGT, g = pair - img*NGT;
  const float* gb = gt + (size_t)(img*NGT + g)*4;
  float tcx = (gb[0]+gb[2])*0.5f, tcy = (gb[1]+gb[3])*0.5f;

  int jx0 = (int)(tcx * 0.125f),   iy0 = (int)(tcy * 0.125f);
  int jx1 = (int)(tcx * 0.0625f),  iy1 = (int)(tcy * 0.0625f);
  int jx2 = (int)(tcx * 0.03125f), iy2 = (int)(tcy * 0.03125f);

  const float4* bb = boxes + (size_t)img*NA;

  float d0=FLT_MAX,d1=FLT_MAX,d2=FLT_MAX,d3=FLT_MAX;
  int   a0,a1,a2,a3;
  #pragma unroll
  for (int s=0; s<4; s++){
    int c = lane + 64*s;
    float dd = FLT_MAX; int aa = 9000000 + c;
    int i, j, S, base, valid = 1;
    if (c < 169)      { int r=c/13,  q=c-13*r;           i=iy0-6+r; j=jx0-6+q; S=80; base=0; }
    else if (c < 218) { int t=c-169; int r=t/7, q=t-7*r; i=iy1-3+r; j=jx1-3+q; S=40; base=6400; }
    else if (c < 243) { int t=c-218; int r=t/5, q=t-5*r; i=iy2-2+r; j=jx2-2+q; S=20; base=8000; }
    else { valid = 0; i=j=0; S=1; base=0; }
    if (valid && i>=0 && i<S && j>=0 && j<S){
      int anchor = base + i*S + j;
      float4 b = bb[anchor];
      float dx=b.x-tcx, dy=b.y-tcy;
      dd = dx*dx + dy*dy;
      aa = anchor;
    }
    if (s==0){ d0=dd; a0=aa; } else if (s==1){ d1=dd; a1=aa; }
    else if (s==2){ d2=dd; a2=aa; } else { d3=dd; a3=aa; }
  }

  for (int r=0; r<KNN; r++){
    float v = d0; int anc = a0;
    if (d1 < v || (d1==v && a1<anc)){ v=d1; anc=a1; }
    if (d2 < v || (d2==v && a2<anc)){ v=d2; anc=a2; }
    if (d3 < v || (d3==v && a3<anc)){ v=d3; anc=a3; }
    #pragma unroll
    for (int off=32; off>0; off>>=1){
      float v2 = __shfl_xor(v, off);
      int  A2 = __shfl_xor(anc, off);
      if (v2 < v || (v2==v && A2<anc)){ v=v2; anc=A2; }
    }
    if (a0==anc) d0=FLT_MAX;
    if (a1==anc) d1=FLT_MAX;
    if (a2==anc) d2=FLT_MAX;
    if (a3==anc) d3=FLT_MAX;
    if (lane == 0) cand[(size_t)pair*KNN + r] = anc;
  }
}

// one BLOCK per (img,gt): 256 threads scan 600 candidates
__global__ __launch_bounds__(256) void match_kernel(const float4* __restrict__ boxes,
                                                    const int* __restrict__ cand,
                                                    const float* __restrict__ gt,
                                                    const int* __restrict__ labels,
                                                    const float* __restrict__ p0,
                                                    const float* __restrict__ p1,
                                                    const float* __restrict__ p2,
                                                    int* __restrict__ matched){
  int pair = blockIdx.x;
  int img = pair / NGT, j = pair - img*NGT;
  int tid = threadIdx.x;
  int wid = tid >> 6, lane = tid & 63;
  const float* gb = gt + (size_t)(img*NGT + j)*4;
  float gx=gb[0], gy=gb[1], gz=gb[2], gw=gb[3];
  float a2 = fmaxf(gz-gx,0.f)*fmaxf(gw-gy,0.f);
  int lab = labels[img*NGT + j];

  const int* ci = cand + (size_t)img*NCAND;
  float best = FLT_MAX; int bslot = 1<<30; int banchor = -1;
  for (int c=tid; c<NCAND; c+=256){
    int a = ci[c];
    float4 b = boxes[(size_t)img*NA + a];
    float bx1=b.x-b.z*0.5f, by1=b.y-b.w*0.5f, bx2=b.x+b.z*0.5f, by2=b.y+b.w*0.5f;
    float a1 = fmaxf(bx2-bx1,0.f)*fmaxf(by2-by1,0.f);
    float ix1=fmaxf(bx1,gx), iy1=fmaxf(by1,gy);
    float ix2=fminf(bx2,gz), iy2=fminf(by2,gw);
    float inter = fmaxf(ix2-ix1,0.f)*fmaxf(iy2-iy1,0.f);
    float uni = a1 + a2 - inter + EPSF;
    float iou = fminf(fmaxf(inter/uni,0.f),1.f);
    float lg = anchor_base(p0,p1,p2,img,a)[4+lab];
    float cost = 0.5f*(1.f - fsigm(lg)) + 6.f*(1.f - iou);
    if (cost < best){ best=cost; bslot=c; banchor=a; }
  }
  #pragma unroll
  for (int off=32; off>0; off>>=1){
    float v2 = __shfl_xor(best, off);
    int  s2 = __shfl_xor(bslot, off);
    int  a2s= __shfl_xor(banchor, off);
    if (v2 < best || (v2==best && s2<bslot)){ best=v2; bslot=s2; banchor=a2s; }
  }
  __shared__ float bc[4]; __shared__ int bs[4], ba[4];
  if (lane == 0){ bc[wid]=best; bs[wid]=bslot; ba[wid]=banchor; }
  __syncthreads();
  if (tid == 0){
    float v=bc[0]; int s=bs[0]; int a=ba[0];
    #pragma unroll
    for (int k=1;k<4;k++){
      if (bc[k] < v || (bc[k]==v && bs[k]<s)){ v=bc[k]; s=bs[k]; a=ba[k]; }
    }
    matched[img*NGT + j] = a;
  }
}

// single block, 16 waves (one image each): ciou + dedup'd corrections + focal
// partial reduction + final scalar
__global__ __launch_bounds__(1024) void tail_kernel(const float4* __restrict__ boxes,
                                                    const int* __restrict__ matched_g,
                                                    const float* __restrict__ gt,
                                                    const int* __restrict__ labels,
                                                    const float* __restrict__ p0,
                                                    const float* __restrict__ p1,
                                                    const float* __restrict__ p2,
                                                    const float* __restrict__ fsum,
                                                    float* __restrict__ out){
  int tid = threadIdx.x;
  int wid = tid >> 6;        // image
  int lane = tid & 63;
  __shared__ int sm[NB][NGT];
  __shared__ int sl[NB][NGT];
  __shared__ float wb[NB], wc[NB], wf[NB];
  if (lane < NGT){
    sm[wid][lane] = matched_g[wid*NGT + lane];
    sl[wid][lane] = labels[wid*NGT + lane];
  }
  __syncthreads();

  int img = wid;
  float local_box = 0.f, local_corr = 0.f;
  if (lane < NGT){
    int j = lane;
    int m = sm[img][j];
    float4 pb = boxes[(size_t)img*NA + m];
    float px1=pb.x-pb.z*0.5f, py1=pb.y-pb.w*0.5f, px2=pb.x+pb.z*0.5f, py2=pb.y+pb.w*0.5f;
    const float* gb = gt + (size_t)(img*NGT + j)*4;
    float gx=gb[0], gy=gb[1], gz=gb[2], gw=gb[3];
    float pw=fmaxf(px2-px1,EPSF), ph=fmaxf(py2-py1,EPSF);
    float tw=fmaxf(gz-gx,EPSF),  th=fmaxf(gw-gy,EPSF);
    float inter = fmaxf(fminf(px2,gz)-fmaxf(px1,gx),0.f)*fmaxf(fminf(py2,gw)-fmaxf(py1,gy),0.f);
    float uni = pw*ph + tw*th - inter + EPSF;
    float iou = inter/uni;
    float dcx = (px1+px2)*0.5f - (gx+gz)*0.5f;
    float dcy = (py1+py2)*0.5f - (gy+gw)*0.5f;
    float cd = dcx*dcx + dcy*dcy;
    float cw = fmaxf(px2,gz) - fminf(px1,gx);
    float ch = fmaxf(py2,gw) - fminf(py1,gy);
    float c2 = cw*cw + ch*ch + EPSF;
    float dv = atanf(tw/th) - atanf(pw/ph);
    float v  = (4.f/(PIF*PIF))*dv*dv;
    float alpha = v/(v - iou + 1.f + EPSF);
    float ciou = iou - cd/c2 - alpha*v;
    local_box = 1.f - ciou;

    int lab = sl[img][j];
    bool dup = false;
    for (int j2=0; j2<j; j2++)
      if (sm[img][j2]==m && sl[img][j2]==lab){ dup=true; break; }
    if (!dup){
      float x = anchor_base(p0,p1,p2,img,m)[4+lab];
      float s  = fsigm(x);
      float u  = fexp2(-fabsf(x)*LOG2E);
      float lt = LN2*flog2(1.0f + u);
      float sp_pos = fmaxf(-x,0.f) + lt;   // softplus(-x) = ce for tgt=1
      float sp_neg = fmaxf( x,0.f) + lt;   // softplus(x)  = ce for tgt=0
      local_corr = 0.25f*sp_pos*(1.f-s)*(1.f-s) - 0.75f*sp_neg*s*s;
    }
  }
  float local_f = fsum[tid] + fsum[tid + 1024];
  #pragma unroll
  for (int off=32; off>0; off>>=1){
    local_box  += __shfl_xor(local_box,  off);
    local_corr += __shfl_xor(local_corr, off);
    local_f    += __shfl_xor(local_f,    off);
  }
  if (lane == 0){ wb[wid]=local_box; wc[wid]=local_corr; wf[wid]=local_f; }
  __syncthreads();
  if (tid == 0){
    float sb=0.f, sc=0.f, sf=0.f;
    #pragma unroll
    for (int k=0;k<NB;k++){ sb+=wb[k]; sc+=wc[k]; sf+=wf[k]; }
    out[0] = (7.5f*sb + 0.5f*(sf + sc)) / (60.f*16.f);
  }
}

extern "C" void kernel_launch(void* const* d_in, const int* in_sizes, int n_in,
                              void* d_out, int out_size, void* d_ws, size_t ws_size,
                              hipStream_t stream){
  const float* p0 = (const float*)d_in[0];
  const float* p1 = (const float*)d_in[1];
  const float* p2 = (const float*)d_in[2];
  const float* gt = (const float*)d_in[3];
  const int* labels = (const int*)d_in[4];
  float* out = (float*)d_out;

  float4* boxes   = (float4*)d_ws;                                       // 2.15 MB
  int*    cand    = (int*)((char*)d_ws + (size_t)NB*NA*sizeof(float4));
  int*    matched = (int*)((char*)cand + (size_t)NB*NCAND*sizeof(int));
  float*  fsum    = (float*)((char*)matched + (size_t)NB*NGT*sizeof(int));

  fused_decode_focal<<<FOCAL_BLOCKS, 256, 0, stream>>>(p0, p1, p2, boxes, fsum);
  topk_kernel<<<NB*NGT/4, 256, 0, stream>>>(boxes, gt, cand);
  match_kernel<<<NB*NGT, 256, 0, stream>>>(boxes, cand, gt, labels, p0, p1, p2, matched);
  tail_kernel<<<1, 1024, 0, stream>>>(boxes, matched, gt, labels, p0, p1, p2, fsum, out);
}